// Round 4
// baseline (386.951 us; speedup 1.0000x reference)
//
#include <hip/hip_runtime.h>

// ---- problem constants (from reference) ----
#define TSTEPS 256
#define NPOP 4
#define NI 8
#define NR 8
#define NO 4
#define NF 28            // NI + 2*NR + NO
#define RANDN 512
#define NBATCH 64
#define NSTATES (NPOP*RANDN)   // 2048
#define THREADS 512
#define SPT 4                  // states per thread
#define ALPHA 0.2f             // DT/TAU
#define ONEMA 0.8f

__device__ __forceinline__ float vexp2(float x) { return __builtin_amdgcn_exp2f(x); }
__device__ __forceinline__ float vrcp(float x)  { return __builtin_amdgcn_rcpf(x); }

// tanh(x) = 1 - 2/(e^{2x}+1), e^{2x} = 2^{x*2*log2(e)}
__device__ __forceinline__ float ftanh(float x) {
    float t = vexp2(x * 2.885390081777927f);
    return __builtin_fmaf(-2.0f, vrcp(t + 1.0f), 1.0f);
}

template<int CTRL, int RM, int BM>
__device__ __forceinline__ float dpp_add(float x) {
    int v = __builtin_amdgcn_update_dpp(0, __float_as_int(x), CTRL, RM, BM, true);
    return x + __int_as_float(v);
}

// full wave64 sum -> result valid in lane 63
__device__ __forceinline__ float wave_red_sum(float x) {
    x = dpp_add<0x111, 0xf, 0xf>(x);  // row_shr:1
    x = dpp_add<0x112, 0xf, 0xf>(x);  // row_shr:2
    x = dpp_add<0x114, 0xf, 0xf>(x);  // row_shr:4
    x = dpp_add<0x118, 0xf, 0xf>(x);  // row_shr:8
    x = dpp_add<0x142, 0xa, 0xf>(x);  // row_bcast:15 -> rows 1,3
    x = dpp_add<0x143, 0xc, 0xf>(x);  // row_bcast:31 -> rows 2,3
    return x;
}

// sum within each 8-lane group -> valid at lanes 8g+7 (shr never pulls from
// below the group into the tail lane's summation tree)
__device__ __forceinline__ float red8(float x) {
    x = dpp_add<0x111, 0xf, 0xf>(x);
    x = dpp_add<0x112, 0xf, 0xf>(x);
    x = dpp_add<0x114, 0xf, 0xf>(x);
    return x;
}

// barrier with LDS-only ordering: do NOT drain vmcnt (keeps HBM noise
// prefetch + phi stores in flight across the barrier).
__device__ __forceinline__ void lds_barrier() {
    asm volatile("s_waitcnt lgkmcnt(0)\n\ts_barrier" ::: "memory");
}

__device__ __forceinline__ float readlane_f(float x, int l) {
    return __uint_as_float(__builtin_amdgcn_readlane(__float_as_uint(x), l));
}

template<bool YHIST>
__global__ __attribute__((amdgpu_flat_work_group_size(THREADS, THREADS),
                          amdgpu_waves_per_eu(2, 2)))
void rnn_fused(
    const float* __restrict__ u,      // [B][T][NI]
    const float* __restrict__ G,      // [NPOP]
    const float* __restrict__ mu,     // [NPOP][NF]
    const float* __restrict__ C,      // [NPOP][NF][NF]
    const float* __restrict__ h0,     // [NPOP][RANDN]
    const float* __restrict__ nl,     // [NPOP][RANDN][NF]
    const float* __restrict__ nrec,   // [B][T][NPOP][RANDN]
    float* __restrict__ phi_hist,     // [B][T][NSTATES] scratch (YHIST only)
    float* __restrict__ y)            // [B][T+1][NO]
{
    __shared__ float u_lds[TSTEPS * NI];                    // 8 KB
    __shared__ float c_lds[NPOP * NF * NF];                 // 12.25 KB
    __shared__ float mu_lds[NPOP * NF];
    __shared__ __align__(16) float part[2][8][8];           // kappa partials, dbuf
    __shared__ __align__(16) float ybuf[TSTEPS + 1][8][4];  // per-wave y partials

    const int tid  = threadIdx.x;
    const int b    = blockIdx.x;
    const int lane = tid & 63;
    const int wid  = tid >> 6;
    const int p    = tid >> 7;          // 128 threads per population
    const int s0   = tid * SPT;         // first global state index

    // ---- stage u[b] into LDS ----
    {
        const float4* src = (const float4*)(u + (size_t)b * TSTEPS * NI);
        ((float4*)u_lds)[tid] = src[tid];
    }
    // ---- stage C into LDS ----
    {
        const float4* src = (const float4*)C;
        float4* dst = (float4*)c_lds;
        #pragma unroll
        for (int i = 0; i < 2; ++i) {
            int idx = tid + i * THREADS;
            if (idx < NPOP * NF * NF / 4) dst[idx] = src[idx];
        }
    }
    if (tid < NPOP * NF) mu_lds[tid] = mu[tid];

    // ---- softmax(G)/RANDN ----
    float w_p;
    {
        float g0 = G[0], g1 = G[1], g2 = G[2], g3 = G[3];
        float m = fmaxf(fmaxf(g0, g1), fmaxf(g2, g3));
        const float L2E = 1.4426950408889634f;
        float e0 = vexp2((g0 - m) * L2E), e1 = vexp2((g1 - m) * L2E);
        float e2 = vexp2((g2 - m) * L2E), e3 = vexp2((g3 - m) * L2E);
        float inv = vrcp(e0 + e1 + e2 + e3);
        float ap = (p == 0) ? e0 : (p == 1) ? e1 : (p == 2) ? e2 : e3;
        w_p = ap * inv * (1.0f / (float)RANDN);
    }
    __syncthreads();

    // ---- loading rows: W[k][f] = mu + C·noise, scaled ----
    // f in [0,8)=alpha*I, [8,16)=alpha*U, [16,24)=w*V, [24,28)=w*O
    float W[SPT][NF];
    #pragma unroll
    for (int f = 0; f < NF; ++f) {
        float m = mu_lds[p * NF + f];
        W[0][f] = m; W[1][f] = m; W[2][f] = m; W[3][f] = m;
    }
    #pragma unroll
    for (int pr = 0; pr < 2; ++pr) {
        float nlr[2][NF];
        #pragma unroll
        for (int kk = 0; kk < 2; ++kk) {
            const float4* src = (const float4*)(nl + (size_t)(s0 + pr * 2 + kk) * NF);
            #pragma unroll
            for (int q = 0; q < 7; ++q) {
                float4 v = src[q];
                nlr[kk][q*4+0] = v.x; nlr[kk][q*4+1] = v.y;
                nlr[kk][q*4+2] = v.z; nlr[kk][q*4+3] = v.w;
            }
        }
        #pragma unroll
        for (int f = 0; f < NF; ++f) {
            const float4* cr = (const float4*)&c_lds[(p * NF + f) * NF];
            float crow[NF];
            #pragma unroll
            for (int q = 0; q < 7; ++q) {
                float4 v = cr[q];
                crow[q*4+0] = v.x; crow[q*4+1] = v.y;
                crow[q*4+2] = v.z; crow[q*4+3] = v.w;
            }
            #pragma unroll
            for (int kk = 0; kk < 2; ++kk) {
                float acc = W[pr*2+kk][f];
                #pragma unroll
                for (int ss = 0; ss < NF; ++ss)
                    acc = __builtin_fmaf(crow[ss], nlr[kk][ss], acc);
                W[pr*2+kk][f] = acc;
            }
        }
    }
    #pragma unroll
    for (int k = 0; k < SPT; ++k) {
        #pragma unroll
        for (int f = 0; f < 16; ++f) W[k][f] *= ALPHA;
        #pragma unroll
        for (int f = 16; f < NF; ++f) W[k][f] *= w_p;
    }

    // ---- init h, depth-2 noise prefetch ----
    float h[SPT];
    {
        float4 v = *(const float4*)(h0 + s0);
        h[0] = v.x; h[1] = v.y; h[2] = v.z; h[3] = v.w;
    }
    const float4* npf = (const float4*)nrec + (size_t)b * (TSTEPS * NSTATES / 4) + tid;
    float4 nbuf0 = npf[0];
    float4 nbuf1 = npf[NSTATES / 4];
    float* yout = y + (size_t)b * (TSTEPS + 1) * NO;
    float4* phw = (float4*)phi_hist + (size_t)b * (TSTEPS * NSTATES / 4) + tid;

    const int s2addr = ((lane & 7) << 3) | (lane >> 3);   // part[w=lane&7][v=lane>>3]

    // ---- main sequential loop: ONE barrier/step, vmcnt never drained ----
    #pragma unroll 2
    for (int t = 0; t < TSTEPS; ++t) {
        float4 nn4 = nbuf0;
        int tp = (t + 2 < TSTEPS) ? (t + 2) : (TSTEPS - 1);
        nbuf0 = nbuf1;
        nbuf1 = npf[(size_t)tp * (NSTATES / 4)];

        float phi0 = ftanh(h[0]), phi1 = ftanh(h[1]);
        float phi2 = ftanh(h[2]), phi3 = ftanh(h[3]);
        if constexpr (YHIST) {
            phw[(size_t)t * (NSTATES / 4)] = float4{phi0, phi1, phi2, phi3};
        }

        // kappa partials over this thread's 4 states
        float kred[8];
        #pragma unroll
        for (int r = 0; r < 8; ++r)
            kred[r] = __builtin_fmaf(phi0, W[0][16+r],
                      __builtin_fmaf(phi1, W[1][16+r],
                      __builtin_fmaf(phi2, W[2][16+r], phi3 * W[3][16+r])));
        #pragma unroll
        for (int i = 0; i < 8; ++i) kred[i] = wave_red_sum(kred[i]);

        if constexpr (!YHIST) {
            float yred[4];
            #pragma unroll
            for (int o = 0; o < 4; ++o)
                yred[o] = __builtin_fmaf(phi0, W[0][24+o],
                          __builtin_fmaf(phi1, W[1][24+o],
                          __builtin_fmaf(phi2, W[2][24+o], phi3 * W[3][24+o])));
            #pragma unroll
            for (int o = 0; o < 4; ++o) yred[o] = wave_red_sum(yred[o]);
            if (lane == 63)
                *(float4*)&ybuf[t][wid][0] = float4{yred[0], yred[1], yred[2], yred[3]};
        }
        if (lane == 63) {
            *(float4*)&part[t & 1][wid][0] = float4{kred[0], kred[1], kred[2], kred[3]};
            *(float4*)&part[t & 1][wid][4] = float4{kred[4], kred[5], kred[6], kred[7]};
        }

        // pre-barrier: base[k] = ONEMA*h + ALPHA*noise + drive  (kappa-independent)
        float ut[8];
        {
            const float4* up = (const float4*)&u_lds[t * NI];
            float4 a = up[0], bb = up[1];
            ut[0]=a.x; ut[1]=a.y; ut[2]=a.z; ut[3]=a.w;
            ut[4]=bb.x; ut[5]=bb.y; ut[6]=bb.z; ut[7]=bb.w;
        }
        float nn[4] = {nn4.x, nn4.y, nn4.z, nn4.w};
        float base[SPT];
        #pragma unroll
        for (int k = 0; k < SPT; ++k) {
            float acc0 = __builtin_fmaf(ALPHA, nn[k], 0.0f);
            acc0 = __builtin_fmaf(ut[0], W[k][0], acc0);
            acc0 = __builtin_fmaf(ut[1], W[k][1], acc0);
            acc0 = __builtin_fmaf(ut[2], W[k][2], acc0);
            acc0 = __builtin_fmaf(ut[3], W[k][3], acc0);
            float acc1 = ut[4] * W[k][4];
            acc1 = __builtin_fmaf(ut[5], W[k][5], acc1);
            acc1 = __builtin_fmaf(ut[6], W[k][6], acc1);
            acc1 = __builtin_fmaf(ut[7], W[k][7], acc1);
            base[k] = __builtin_fmaf(ONEMA, h[k], acc0 + acc1);
        }
        lds_barrier();

        // stage 2: 1 ds_read (2-way alias, free) + red8 DPP + readlane -> SGPR kf
        float pv = (&part[t & 1][0][0])[s2addr];
        pv = red8(pv);
        float kf0 = readlane_f(pv, 7),  kf1 = readlane_f(pv, 15);
        float kf2 = readlane_f(pv, 23), kf3 = readlane_f(pv, 31);
        float kf4 = readlane_f(pv, 39), kf5 = readlane_f(pv, 47);
        float kf6 = readlane_f(pv, 55), kf7 = readlane_f(pv, 63);

        #pragma unroll
        for (int k = 0; k < SPT; ++k) {
            float r0 = kf0 * W[k][8];
            r0 = __builtin_fmaf(kf1, W[k][9],  r0);
            r0 = __builtin_fmaf(kf2, W[k][10], r0);
            r0 = __builtin_fmaf(kf3, W[k][11], r0);
            float r1 = kf4 * W[k][12];
            r1 = __builtin_fmaf(kf5, W[k][13], r1);
            r1 = __builtin_fmaf(kf6, W[k][14], r1);
            r1 = __builtin_fmaf(kf7, W[k][15], r1);
            h[k] = base[k] + (r0 + r1);
        }
    }

    // ---- final y partials from h_T (row T goes straight to ybuf) ----
    {
        float phi0 = ftanh(h[0]), phi1 = ftanh(h[1]);
        float phi2 = ftanh(h[2]), phi3 = ftanh(h[3]);
        float yred[4];
        #pragma unroll
        for (int o = 0; o < 4; ++o)
            yred[o] = __builtin_fmaf(phi0, W[0][24+o],
                      __builtin_fmaf(phi1, W[1][24+o],
                      __builtin_fmaf(phi2, W[2][24+o], phi3 * W[3][24+o])));
        #pragma unroll
        for (int o = 0; o < 4; ++o) yred[o] = wave_red_sum(yred[o]);
        if (lane == 63)
            *(float4*)&ybuf[TSTEPS][wid][0] = float4{yred[0], yred[1], yred[2], yred[3]};
    }

    if constexpr (YHIST) {
        // drain phi stores, then post-pass: y[t] = sum_s phi[t][s] * Ow[s]
        asm volatile("s_waitcnt vmcnt(0)" ::: "memory");
        __syncthreads();
        const float4* phr = (const float4*)phi_hist + (size_t)b * (TSTEPS * NSTATES / 4) + tid;
        float4 pp0 = phr[0];
        float4 pp1 = phr[NSTATES / 4];
        #pragma unroll 2
        for (int t = 0; t < TSTEPS; ++t) {
            float4 pv4 = pp0;
            int tp = (t + 2 < TSTEPS) ? (t + 2) : (TSTEPS - 1);
            pp0 = pp1;
            pp1 = phr[(size_t)tp * (NSTATES / 4)];
            float yred[4];
            #pragma unroll
            for (int o = 0; o < 4; ++o)
                yred[o] = __builtin_fmaf(pv4.x, W[0][24+o],
                          __builtin_fmaf(pv4.y, W[1][24+o],
                          __builtin_fmaf(pv4.z, W[2][24+o], pv4.w * W[3][24+o])));
            #pragma unroll
            for (int o = 0; o < 4; ++o) yred[o] = wave_red_sum(yred[o]);
            if (lane == 63)
                *(float4*)&ybuf[t][wid][0] = float4{yred[0], yred[1], yred[2], yred[3]};
        }
    }
    lds_barrier();

    // ---- final y reduction: 1028 outputs, each sum of 8 wave partials ----
    for (int idx = tid; idx < (TSTEPS + 1) * NO; idx += THREADS) {
        int t = idx >> 2, o = idx & 3;
        float s = ((ybuf[t][0][o] + ybuf[t][1][o]) + (ybuf[t][2][o] + ybuf[t][3][o]))
                + ((ybuf[t][4][o] + ybuf[t][5][o]) + (ybuf[t][6][o] + ybuf[t][7][o]));
        yout[idx] = s;
    }
}

extern "C" void kernel_launch(void* const* d_in, const int* in_sizes, int n_in,
                              void* d_out, int out_size, void* d_ws, size_t ws_size,
                              hipStream_t stream) {
    const float* u    = (const float*)d_in[0];
    const float* G    = (const float*)d_in[1];
    const float* mu   = (const float*)d_in[2];
    const float* C    = (const float*)d_in[3];
    const float* h0   = (const float*)d_in[4];
    const float* nl   = (const float*)d_in[5];
    const float* nrec = (const float*)d_in[6];
    float* y = (float*)d_out;

    const size_t need = (size_t)NBATCH * TSTEPS * NSTATES * sizeof(float); // 128 MiB
    if (ws_size >= need) {
        rnn_fused<true><<<dim3(NBATCH), dim3(THREADS), 0, stream>>>(
            u, G, mu, C, h0, nl, nrec, (float*)d_ws, y);
    } else {
        rnn_fused<false><<<dim3(NBATCH), dim3(THREADS), 0, stream>>>(
            u, G, mu, C, h0, nl, nrec, nullptr, y);
    }
}

// Round 5
// 300.415 us; speedup vs baseline: 1.2881x; 1.2881x over previous
//
#include <hip/hip_runtime.h>

// ---- problem constants (from reference) ----
#define TSTEPS 256
#define NPOP 4
#define NI 8
#define NR 8
#define NO 4
#define NF 28            // NI + 2*NR + NO
#define RANDN 512
#define NBATCH 64
#define NSTATES (NPOP*RANDN)   // 2048
#define THREADS 256
#define NWAVES (THREADS/64)    // 4 waves; wave w owns population w
#define SPT 8                  // states per thread
#define ALPHA 0.2f             // DT/TAU
#define ONEMA 0.8f

__device__ __forceinline__ float vexp2(float x) { return __builtin_amdgcn_exp2f(x); }
__device__ __forceinline__ float vrcp(float x)  { return __builtin_amdgcn_rcpf(x); }

// tanh(x) = 1 - 2/(e^{2x}+1), e^{2x} = 2^{x*2*log2(e)}
__device__ __forceinline__ float ftanh(float x) {
    float t = vexp2(x * 2.885390081777927f);
    return __builtin_fmaf(-2.0f, vrcp(t + 1.0f), 1.0f);
}

template<int CTRL, int RM, int BM>
__device__ __forceinline__ float dpp_add(float x) {
    int v = __builtin_amdgcn_update_dpp(0, __float_as_int(x), CTRL, RM, BM, true);
    return x + __int_as_float(v);
}

// full wave64 sum -> result valid in lane 63
__device__ __forceinline__ float wave_red_sum(float x) {
    x = dpp_add<0x111, 0xf, 0xf>(x);  // row_shr:1
    x = dpp_add<0x112, 0xf, 0xf>(x);  // row_shr:2
    x = dpp_add<0x114, 0xf, 0xf>(x);  // row_shr:4
    x = dpp_add<0x118, 0xf, 0xf>(x);  // row_shr:8
    x = dpp_add<0x142, 0xa, 0xf>(x);  // row_bcast:15 -> rows 1,3
    x = dpp_add<0x143, 0xc, 0xf>(x);  // row_bcast:31 -> rows 2,3
    return x;
}

// sum within each 4-lane group -> valid at lanes 4g+3
__device__ __forceinline__ float red4(float x) {
    x = dpp_add<0x111, 0xf, 0xf>(x);
    x = dpp_add<0x112, 0xf, 0xf>(x);
    return x;
}

// barrier with LDS-only ordering: do NOT drain vmcnt (keeps the HBM noise
// prefetch in flight across the barrier). All in-loop cross-thread data is LDS.
__device__ __forceinline__ void lds_barrier() {
    asm volatile("s_waitcnt lgkmcnt(0)\n\ts_barrier" ::: "memory");
}

__device__ __forceinline__ float readlane_f(float x, int l) {
    return __uint_as_float(__builtin_amdgcn_readlane(__float_as_uint(x), l));
}

__global__ __launch_bounds__(THREADS, 1)   // min 1 wave/EU -> 512-VGPR budget: keep W out of AGPRs
void rnn_fused(
    const float* __restrict__ u,      // [B][T][NI]
    const float* __restrict__ G,      // [NPOP]
    const float* __restrict__ mu,     // [NPOP][NF]
    const float* __restrict__ C,      // [NPOP][NF][NF]
    const float* __restrict__ h0,     // [NPOP][RANDN]
    const float* __restrict__ nl,     // [NPOP][RANDN][NF]
    const float* __restrict__ nrec,   // [B][T][NPOP][RANDN]
    float* __restrict__ y)            // [B][T+1][NO]
{
    __shared__ float u_lds[TSTEPS * NI];                       // 8 KB
    __shared__ float c_lds[NPOP * NF * NF];                    // 12.25 KB
    __shared__ float mu_lds[NPOP * NF];
    __shared__ __align__(16) float part[2][NWAVES][8];         // kappa partials, dbuf
    __shared__ __align__(16) float ybuf[TSTEPS + 1][NWAVES][4];// per-wave y partials

    const int tid  = threadIdx.x;
    const int b    = blockIdx.x;
    const int lane = tid & 63;
    const int wid  = tid >> 6;          // == population p (64 threads x 8 states = 512)
    const int s0   = tid * SPT;         // first global state index

    // ---- stage u[b] into LDS (512 float4) ----
    {
        const float4* src = (const float4*)(u + (size_t)b * TSTEPS * NI);
        ((float4*)u_lds)[tid]           = src[tid];
        ((float4*)u_lds)[tid + THREADS] = src[tid + THREADS];
    }
    // ---- stage C into LDS (784 float4) ----
    {
        const float4* src = (const float4*)C;
        float4* dst = (float4*)c_lds;
        #pragma unroll
        for (int i = 0; i < 4; ++i) {
            int idx = tid + i * THREADS;
            if (idx < NPOP * NF * NF / 4) dst[idx] = src[idx];
        }
    }
    if (tid < NPOP * NF) mu_lds[tid] = mu[tid];

    // ---- softmax(G)/RANDN for this wave's population ----
    float w_p;
    {
        float g0 = G[0], g1 = G[1], g2 = G[2], g3 = G[3];
        float m = fmaxf(fmaxf(g0, g1), fmaxf(g2, g3));
        const float L2E = 1.4426950408889634f;
        float e0 = vexp2((g0 - m) * L2E), e1 = vexp2((g1 - m) * L2E);
        float e2 = vexp2((g2 - m) * L2E), e3 = vexp2((g3 - m) * L2E);
        float inv = vrcp(e0 + e1 + e2 + e3);
        float ap = (wid == 0) ? e0 : (wid == 1) ? e1 : (wid == 2) ? e2 : e3;
        w_p = ap * inv * (1.0f / (float)RANDN);
    }
    __syncthreads();

    // ---- loading rows: W[k][f] = mu + C·noise, scaled ----
    // f in [0,8)=alpha*I, [8,16)=alpha*U, [16,24)=w*V, [24,28)=w*O
    float W[SPT][NF];
    #pragma unroll
    for (int f = 0; f < NF; ++f) {
        float m = mu_lds[wid * NF + f];
        #pragma unroll
        for (int k = 0; k < SPT; ++k) W[k][f] = m;
    }
    #pragma unroll
    for (int pr = 0; pr < 2; ++pr) {       // 4 states at a time
        float nlr[4][NF];
        #pragma unroll
        for (int kk = 0; kk < 4; ++kk) {
            const float4* src = (const float4*)(nl + (size_t)(s0 + pr * 4 + kk) * NF);
            #pragma unroll
            for (int q = 0; q < 7; ++q) {
                float4 v = src[q];
                nlr[kk][q*4+0] = v.x; nlr[kk][q*4+1] = v.y;
                nlr[kk][q*4+2] = v.z; nlr[kk][q*4+3] = v.w;
            }
        }
        #pragma unroll
        for (int f = 0; f < NF; ++f) {
            const float4* cr = (const float4*)&c_lds[(wid * NF + f) * NF];
            float crow[NF];
            #pragma unroll
            for (int q = 0; q < 7; ++q) {
                float4 v = cr[q];
                crow[q*4+0] = v.x; crow[q*4+1] = v.y;
                crow[q*4+2] = v.z; crow[q*4+3] = v.w;
            }
            #pragma unroll
            for (int kk = 0; kk < 4; ++kk) {
                float acc = W[pr*4+kk][f];
                #pragma unroll
                for (int ss = 0; ss < NF; ++ss)
                    acc = __builtin_fmaf(crow[ss], nlr[kk][ss], acc);
                W[pr*4+kk][f] = acc;
            }
        }
    }
    #pragma unroll
    for (int k = 0; k < SPT; ++k) {
        #pragma unroll
        for (int f = 0; f < 16; ++f) W[k][f] *= ALPHA;
        #pragma unroll
        for (int f = 16; f < NF; ++f) W[k][f] *= w_p;
    }

    // ---- init h, depth-2 noise prefetch (2 float4 per step per thread) ----
    float h[SPT];
    {
        const float4* hp = (const float4*)(h0 + s0);
        float4 v0 = hp[0], v1 = hp[1];
        h[0]=v0.x; h[1]=v0.y; h[2]=v0.z; h[3]=v0.w;
        h[4]=v1.x; h[5]=v1.y; h[6]=v1.z; h[7]=v1.w;
    }
    const float4* nbase = (const float4*)nrec + (size_t)b * (TSTEPS * NSTATES / 4) + tid * 2;
    float4 nA0 = nbase[0], nA1 = nbase[1];                              // t=0
    float4 nB0 = nbase[NSTATES / 4], nB1 = nbase[NSTATES / 4 + 1];      // t=1
    float* yout = y + (size_t)b * (TSTEPS + 1) * NO;

    const int s2addr = ((lane & 3) << 3) | (lane >> 3);   // part[w=lane&3][v=lane>>3]

    // ---- step body: uses (nc0,nc1) as this step's noise, refills them with t+2 ----
    auto STEP = [&](int t, float4& nc0, float4& nc1) {
        float4 u0 = nc0, u1 = nc1;
        int tp = (t + 2 < TSTEPS) ? (t + 2) : (TSTEPS - 1);
        nc0 = nbase[(size_t)tp * (NSTATES / 4)];
        nc1 = nbase[(size_t)tp * (NSTATES / 4) + 1];

        float phi[SPT];
        #pragma unroll
        for (int k = 0; k < SPT; ++k) phi[k] = ftanh(h[k]);

        // kappa partials (8) + y partials (4) over this thread's 8 states
        float red[12];
        #pragma unroll
        for (int r = 0; r < 8; ++r) {
            float a = phi[0] * W[0][16 + r];
            #pragma unroll
            for (int k = 1; k < SPT; ++k) a = __builtin_fmaf(phi[k], W[k][16 + r], a);
            red[r] = a;
        }
        #pragma unroll
        for (int o = 0; o < 4; ++o) {
            float a = phi[0] * W[0][24 + o];
            #pragma unroll
            for (int k = 1; k < SPT; ++k) a = __builtin_fmaf(phi[k], W[k][24 + o], a);
            red[8 + o] = a;
        }
        #pragma unroll
        for (int i = 0; i < 12; ++i) red[i] = wave_red_sum(red[i]);

        if (lane == 63) {
            *(float4*)&part[t & 1][wid][0] = float4{red[0], red[1], red[2], red[3]};
            *(float4*)&part[t & 1][wid][4] = float4{red[4], red[5], red[6], red[7]};
            *(float4*)&ybuf[t][wid][0]     = float4{red[8], red[9], red[10], red[11]};
        }

        // pre-barrier: base[k] = ONEMA*h + ALPHA*noise + drive (kappa-independent)
        float ut[8];
        {
            const float4* up = (const float4*)&u_lds[t * NI];
            float4 a = up[0], bb = up[1];
            ut[0]=a.x; ut[1]=a.y; ut[2]=a.z; ut[3]=a.w;
            ut[4]=bb.x; ut[5]=bb.y; ut[6]=bb.z; ut[7]=bb.w;
        }
        float nn[8] = {u0.x, u0.y, u0.z, u0.w, u1.x, u1.y, u1.z, u1.w};
        float base[SPT];
        #pragma unroll
        for (int k = 0; k < SPT; ++k) {
            float acc0 = ALPHA * nn[k];
            acc0 = __builtin_fmaf(ut[0], W[k][0], acc0);
            acc0 = __builtin_fmaf(ut[1], W[k][1], acc0);
            acc0 = __builtin_fmaf(ut[2], W[k][2], acc0);
            acc0 = __builtin_fmaf(ut[3], W[k][3], acc0);
            float acc1 = ut[4] * W[k][4];
            acc1 = __builtin_fmaf(ut[5], W[k][5], acc1);
            acc1 = __builtin_fmaf(ut[6], W[k][6], acc1);
            acc1 = __builtin_fmaf(ut[7], W[k][7], acc1);
            base[k] = __builtin_fmaf(ONEMA, h[k], acc0 + acc1);
        }
        lds_barrier();

        // stage 2: 1 broadcast ds_read + red4 over the 4 waves + readlane -> SGPR kf
        float pv = (&part[t & 1][0][0])[s2addr];
        pv = red4(pv);
        float kf0 = readlane_f(pv, 3),  kf1 = readlane_f(pv, 11);
        float kf2 = readlane_f(pv, 19), kf3 = readlane_f(pv, 27);
        float kf4 = readlane_f(pv, 35), kf5 = readlane_f(pv, 43);
        float kf6 = readlane_f(pv, 51), kf7 = readlane_f(pv, 59);

        #pragma unroll
        for (int k = 0; k < SPT; ++k) {
            float r0 = kf0 * W[k][8];
            r0 = __builtin_fmaf(kf1, W[k][9],  r0);
            r0 = __builtin_fmaf(kf2, W[k][10], r0);
            r0 = __builtin_fmaf(kf3, W[k][11], r0);
            float r1 = kf4 * W[k][12];
            r1 = __builtin_fmaf(kf5, W[k][13], r1);
            r1 = __builtin_fmaf(kf6, W[k][14], r1);
            r1 = __builtin_fmaf(kf7, W[k][15], r1);
            h[k] = base[k] + (r0 + r1);
        }
    };

    for (int t = 0; t < TSTEPS; t += 2) {
        STEP(t,     nA0, nA1);
        STEP(t + 1, nB0, nB1);
    }

    // ---- final y partials from h_T ----
    {
        float phi[SPT];
        #pragma unroll
        for (int k = 0; k < SPT; ++k) phi[k] = ftanh(h[k]);
        float yred[4];
        #pragma unroll
        for (int o = 0; o < 4; ++o) {
            float a = phi[0] * W[0][24 + o];
            #pragma unroll
            for (int k = 1; k < SPT; ++k) a = __builtin_fmaf(phi[k], W[k][24 + o], a);
            yred[o] = a;
        }
        #pragma unroll
        for (int o = 0; o < 4; ++o) yred[o] = wave_red_sum(yred[o]);
        if (lane == 63)
            *(float4*)&ybuf[TSTEPS][wid][0] = float4{yred[0], yred[1], yred[2], yred[3]};
    }
    lds_barrier();

    // ---- final y reduction: 1028 outputs, each sum of 4 wave partials ----
    for (int idx = tid; idx < (TSTEPS + 1) * NO; idx += THREADS) {
        int t = idx >> 2, o = idx & 3;
        yout[idx] = (ybuf[t][0][o] + ybuf[t][1][o]) + (ybuf[t][2][o] + ybuf[t][3][o]);
    }
}

extern "C" void kernel_launch(void* const* d_in, const int* in_sizes, int n_in,
                              void* d_out, int out_size, void* d_ws, size_t ws_size,
                              hipStream_t stream) {
    const float* u    = (const float*)d_in[0];
    const float* G    = (const float*)d_in[1];
    const float* mu   = (const float*)d_in[2];
    const float* C    = (const float*)d_in[3];
    const float* h0   = (const float*)d_in[4];
    const float* nl   = (const float*)d_in[5];
    const float* nrec = (const float*)d_in[6];
    float* y = (float*)d_out;

    rnn_fused<<<dim3(NBATCH), dim3(THREADS), 0, stream>>>(u, G, mu, C, h0, nl, nrec, y);
}